// Round 2
// baseline (378.737 us; speedup 1.0000x reference)
//
#include <hip/hip_runtime.h>
#include <cstdint>
#include <cstddef>

// ---------- fp16 helpers ----------
typedef __attribute__((ext_vector_type(8))) _Float16 half8;
typedef __attribute__((ext_vector_type(4))) float floatx4;

static __device__ __forceinline__ uint16_t f2h(float f) {
    _Float16 h = (_Float16)f;
    uint16_t u;
    __builtin_memcpy(&u, &h, 2);
    return u;
}
static __device__ __forceinline__ float h2f(uint16_t u) {
    _Float16 h;
    __builtin_memcpy(&h, &u, 2);
    return (float)h;
}

// async global->LDS, 16B per lane. LDS dest must be wave-uniform base + lane*16,
// which our staging layout satisfies exactly (chunk index = wave*64 + lane + s*256).
static __device__ __forceinline__ void g2lds16(const void* g, void* l) {
    __builtin_amdgcn_global_load_lds((__attribute__((address_space(1))) void*)g,
                                     (__attribute__((address_space(3))) void*)l, 16, 0, 0);
}

// ---------- fp32 -> fp16 convert (weights) ----------
__global__ void cvt_f32_f16(const float* __restrict__ in, uint16_t* __restrict__ out, int n) {
    int i = blockIdx.x * blockDim.x + threadIdx.x;
    int base = i * 4;
    if (base < n) {
        float4 v = *(const float4*)(in + base);
        ushort4 u = make_ushort4(f2h(v.x), f2h(v.y), f2h(v.z), f2h(v.w));
        *(ushort4*)(out + base) = u;
    }
}

// ---------- transpose x: (b,512,4096) f32 -> Xt (b,4096,512) f16 ----------
__global__ __launch_bounds__(256) void transpose_x(const float* __restrict__ x, uint16_t* __restrict__ xt) {
    __shared__ uint16_t tile[64][66];
    int b = blockIdx.z, p0 = blockIdx.x * 64, c0 = blockIdx.y * 64;
    int t0 = threadIdx.x & 63, t1 = threadIdx.x >> 6;
    const float* xb = x + ((long)b * 512 + c0) * 4096 + p0;
#pragma unroll
    for (int r = 0; r < 16; ++r) {
        int cc = t1 * 16 + r;
        tile[cc][t0] = f2h(xb[(long)cc * 4096 + t0]);
    }
    __syncthreads();
    uint16_t* xtb = xt + ((long)b * 4096 + p0) * 512 + c0;
#pragma unroll
    for (int r = 0; r < 16; ++r) {
        int pp = t1 * 16 + r;
        xtb[(long)pp * 512 + t0] = tile[t0][pp];
    }
}

// ---------- NT GEMM: C[m][n] = sum_k A[m][k]*B[n][k], fp16 in ----------
// 128x128 tile, BK=32, 4 waves each 64x64 (4x4 of 16x16x32 MFMA).
// KHALF: for k>=256 both A and B row bases shift by 2048 rows, k -= 256 (channel-view split).
// EPI: 0 = fp16 C[m][n]; 1 = fp32 C[m][n] + residual; 2 = fp16 transposed C[n][m] (ldc = n-major stride)
template <bool KHALF, int EPI>
__global__ __launch_bounds__(256) void gemm_nt(const uint16_t* __restrict__ A, const uint16_t* __restrict__ B,
                                               void* __restrict__ Cout, const float* __restrict__ resid,
                                               int lda, int ldb, int ldc, int nK,
                                               long aBatch, long bBatch, long cBatch) {
    __shared__ uint16_t Al[128 * 32];
    __shared__ uint16_t Bl[128 * 32];
    const int b = blockIdx.z;
    const uint16_t* Ab = A + (long)b * aBatch;
    const uint16_t* Bb = B + (long)b * bBatch;
    const int m0 = blockIdx.x * 128, n0 = blockIdx.y * 128;
    const int tid = threadIdx.x;
    const int lane = tid & 63, wave = tid >> 6;
    const int ln = lane & 15, q = lane >> 4;
    const int wm = (wave & 1) * 64, wn = (wave >> 1) * 64;

    floatx4 acc[4][4];
#pragma unroll
    for (int i = 0; i < 4; ++i)
#pragma unroll
        for (int j = 0; j < 4; ++j) acc[i][j] = (floatx4){0.f, 0.f, 0.f, 0.f};

    for (int kt = 0; kt < nK; ++kt) {
        int k0 = kt * 32;
        int keff = k0;
        long roff = 0;
        if (KHALF && k0 >= 256) { keff = k0 - 256; roff = 2048; }
#pragma unroll
        for (int s = 0; s < 2; ++s) {
            int c = tid + s * 256;           // 512 chunks of 16B per operand
            int row = c >> 2, kq = (c & 3) * 8;
            g2lds16(Ab + ((long)(m0 + row) + roff) * lda + keff + kq, &Al[c * 8]);
            g2lds16(Bb + ((long)(n0 + row) + roff) * ldb + keff + kq, &Bl[c * 8]);
        }
        __syncthreads();
        half8 af[4], bfr[4];
#pragma unroll
        for (int mt = 0; mt < 4; ++mt) af[mt] = *(const half8*)&Al[(wm + mt * 16 + ln) * 32 + q * 8];
#pragma unroll
        for (int nt = 0; nt < 4; ++nt) bfr[nt] = *(const half8*)&Bl[(wn + nt * 16 + ln) * 32 + q * 8];
#pragma unroll
        for (int mt = 0; mt < 4; ++mt)
#pragma unroll
            for (int nt = 0; nt < 4; ++nt)
                acc[mt][nt] = __builtin_amdgcn_mfma_f32_16x16x32_f16(af[mt], bfr[nt], acc[mt][nt], 0, 0, 0);
        __syncthreads();
    }

    // C/D layout (verified m89): col = lane&15, row = (lane>>4)*4 + reg
    if (EPI == 0) {
        uint16_t* C = (uint16_t*)Cout + (long)b * cBatch;
#pragma unroll
        for (int mt = 0; mt < 4; ++mt)
#pragma unroll
            for (int r = 0; r < 4; ++r) {
                int gm = m0 + wm + mt * 16 + q * 4 + r;
#pragma unroll
                for (int nt = 0; nt < 4; ++nt) {
                    int gn = n0 + wn + nt * 16 + ln;
                    C[(long)gm * ldc + gn] = f2h(acc[mt][nt][r]);
                }
            }
    } else if (EPI == 1) {
        float* C = (float*)Cout + (long)b * cBatch;
        const float* X = resid + (long)b * cBatch;
#pragma unroll
        for (int mt = 0; mt < 4; ++mt)
#pragma unroll
            for (int r = 0; r < 4; ++r) {
                int gm = m0 + wm + mt * 16 + q * 4 + r;
#pragma unroll
                for (int nt = 0; nt < 4; ++nt) {
                    int gn = n0 + wn + nt * 16 + ln;
                    long idx = (long)gm * ldc + gn;
                    C[idx] = acc[mt][nt][r] + X[idx];
                }
            }
    } else {
        // transposed epilogue: C[n][m], 4 contiguous m per lane -> ushort4 stores
        uint16_t* C = (uint16_t*)Cout + (long)b * cBatch;
#pragma unroll
        for (int nt = 0; nt < 4; ++nt) {
            int gn = n0 + wn + nt * 16 + ln;
#pragma unroll
            for (int mt = 0; mt < 4; ++mt) {
                int gmB = m0 + wm + mt * 16 + q * 4;
                ushort4 u = make_ushort4(f2h(acc[mt][nt][0]), f2h(acc[mt][nt][1]), f2h(acc[mt][nt][2]),
                                         f2h(acc[mt][nt][3]));
                *(ushort4*)&C[(long)gn * ldc + gmB] = u;
            }
        }
    }
}

// ---------- column softmax stats: per (b,j) max_i and 1/sum_i exp over i in [0,2048) ----------
__global__ __launch_bounds__(256) void softmax_stats(const uint16_t* __restrict__ S, float* __restrict__ mOut,
                                                     float* __restrict__ rOut) {
    int b = blockIdx.y;
    int jl = threadIdx.x & 63;
    int s = threadIdx.x >> 6;
    int j = blockIdx.x * 64 + jl;
    const uint16_t* Sb = S + (long)b * 2048 * 2048 + j;
    float m = -1e30f, l = 0.f;
    for (int i = s * 512; i < s * 512 + 512; ++i) {
        float v = h2f(Sb[(long)i * 2048]);
        float mn = fmaxf(m, v);
        l = l * __expf(m - mn) + __expf(v - mn);
        m = mn;
    }
    __shared__ float sm[4][64], sl[4][64];
    sm[s][jl] = m;
    sl[s][jl] = l;
    __syncthreads();
    if (s == 0) {
        float M = sm[0][jl];
        for (int k = 1; k < 4; ++k) M = fmaxf(M, sm[k][jl]);
        float L = 0.f;
        for (int k = 0; k < 4; ++k) L += sl[k][jl] * __expf(sm[k][jl] - M);
        mOut[(long)b * 2048 + j] = M;
        rOut[(long)b * 2048 + j] = 1.f / L;
    }
}

// ---------- in-place P = exp(S - m[j]) * r[j] (fp16 -> fp16) ----------
__global__ void apply_softmax(uint16_t* __restrict__ S, const float* __restrict__ mIn, const float* __restrict__ rIn) {
    long t = (long)blockIdx.x * 256 + threadIdx.x;  // 4,194,304 threads, 8 elems each
    long base = t * 8;
    int j0 = (int)(base & 2047);
    long row = base >> 11;
    int b = (int)(row >> 11);
    const float* mp = mIn + (long)b * 2048 + j0;
    const float* rp = rIn + (long)b * 2048 + j0;
    float4 m0 = *(const float4*)mp, m1 = *(const float4*)(mp + 4);
    float4 r0 = *(const float4*)rp, r1 = *(const float4*)(rp + 4);
    float mv[8] = {m0.x, m0.y, m0.z, m0.w, m1.x, m1.y, m1.z, m1.w};
    float rv[8] = {r0.x, r0.y, r0.z, r0.w, r1.x, r1.y, r1.z, r1.w};
    uint4 v = *(uint4*)(S + base);
    uint32_t* pv = (uint32_t*)&v;
    uint32_t o[4];
#pragma unroll
    for (int k = 0; k < 4; ++k) {
        float a = h2f((uint16_t)(pv[k] & 0xffffu));
        float c = h2f((uint16_t)(pv[k] >> 16));
        float pa = __expf(a - mv[2 * k]) * rv[2 * k];
        float pc = __expf(c - mv[2 * k + 1]) * rv[2 * k + 1];
        o[k] = (uint32_t)f2h(pa) | ((uint32_t)f2h(pc) << 16);
    }
    *(uint4*)(S + base) = *(uint4*)o;
}

// ---------- de-interleave: Yt[b][p][ic] = Y2[b][p%2048][2*ic + p/2048] ----------
__global__ void interleave_y(const uint16_t* __restrict__ y2, uint16_t* __restrict__ yt) {
    long t = (long)blockIdx.x * 256 + threadIdx.x;  // 1,048,576 threads, 8 out elems each
    long obase = t * 8;
    int ic0 = (int)(obase & 255);
    long prow = obase >> 8;  // b*4096 + p
    int p = (int)(prow & 4095);
    int b = (int)(prow >> 12);
    int i = p & 2047, h = p >> 11;
    const uint16_t* src = y2 + ((long)b * 2048 + i) * 512 + 2 * ic0;
    uint4 v0 = *(const uint4*)src;
    uint4 v1 = *(const uint4*)(src + 8);
    uint32_t* a = (uint32_t*)&v0;
    uint32_t* c = (uint32_t*)&v1;
    uint32_t o[4];
    if (h == 0) {
        o[0] = (a[0] & 0xffffu) | (a[1] << 16);
        o[1] = (a[2] & 0xffffu) | (a[3] << 16);
        o[2] = (c[0] & 0xffffu) | (c[1] << 16);
        o[3] = (c[2] & 0xffffu) | (c[3] << 16);
    } else {
        o[0] = (a[0] >> 16) | (a[1] & 0xffff0000u);
        o[1] = (a[2] >> 16) | (a[3] & 0xffff0000u);
        o[2] = (c[0] >> 16) | (c[1] & 0xffff0000u);
        o[3] = (c[2] >> 16) | (c[3] & 0xffff0000u);
    }
    *(uint4*)(yt + obase) = *(uint4*)o;
}

// ---------- launch ----------
// ws layout (total 118,620,160 B = 113.1 MB — kept well under likely 128 MiB ws_size;
// round-0's 202.5 MB overflowed d_ws and corrupted the harness's pristine input copies):
//   W3   @ 0         768x512 f16 (phi rows 0-255, theta 256-511, g 512-767)
//   Wm   @ 786432    512x256 f16
//   mSt  @ 1048576   8x2048 f32
//   rSt  @ 1114112   8x2048 f32
//   A_region @ 1179648  (64 MB): Xt (32 MB) -> S (64 MB) -> Yt (16 MB)
//   B_region @ 68288512 (48 MB): C2 (32 MB) @ +0 -> Y2 (16 MB) @ +0 ; Gc (16 MB) @ +32MB
// Lifetimes: Xt dies when scores overwrite A_region; C2 dies after scores -> Y2 reuses it;
// Gc (written by conv-g transposed epilogue) lives until PV; S dies after PV -> Yt reuses A_region.
extern "C" void kernel_launch(void* const* d_in, const int* in_sizes, int n_in, void* d_out, int out_size, void* d_ws,
                              size_t ws_size, hipStream_t stream) {
    const float* x = (const float*)d_in[0];
    const float* wphi = (const float*)d_in[1];
    const float* wtheta = (const float*)d_in[2];
    const float* wg = (const float*)d_in[3];
    const float* wmask = (const float*)d_in[4];
    float* out = (float*)d_out;
    char* ws = (char*)d_ws;

    uint16_t* W3 = (uint16_t*)(ws + 0);
    uint16_t* Wm = (uint16_t*)(ws + 786432);
    float* mSt = (float*)(ws + 1048576);
    float* rSt = (float*)(ws + 1114112);
    char* A_region = ws + 1179648;
    char* B_region = ws + 68288512;
    uint16_t* Xt = (uint16_t*)A_region;
    uint16_t* S = (uint16_t*)A_region;
    uint16_t* Yt = (uint16_t*)A_region;
    uint16_t* C2 = (uint16_t*)B_region;
    uint16_t* Y2 = (uint16_t*)B_region;
    uint16_t* Gc = (uint16_t*)(B_region + 33554432);

    // weights -> fp16
    cvt_f32_f16<<<128, 256, 0, stream>>>(wphi, W3, 131072);
    cvt_f32_f16<<<128, 256, 0, stream>>>(wtheta, W3 + 131072, 131072);
    cvt_f32_f16<<<128, 256, 0, stream>>>(wg, W3 + 262144, 131072);
    cvt_f32_f16<<<128, 256, 0, stream>>>(wmask, Wm, 131072);

    // x -> Xt (pixel-major fp16)
    transpose_x<<<dim3(64, 8, 8), 256, 0, stream>>>(x, Xt);

    // phi+theta conv: C2[b][p][{phi 0-255 | theta 256-511}]
    gemm_nt<false, 0><<<dim3(32, 4, 8), 256, 0, stream>>>(Xt, W3, C2, nullptr, 512, 512, 512, 16, 4096L * 512, 0,
                                                          4096L * 512);

    // g conv with transposed epilogue -> Gc[b][o][p]
    gemm_nt<false, 2><<<dim3(32, 2, 8), 256, 0, stream>>>(Xt, W3 + 262144, Gc, nullptr, 512, 512, 4096, 16,
                                                          4096L * 512, 0, 256L * 4096);

    // scores: S[i][j] with k-half row shift (channel-view split); overwrites Xt (dead)
    gemm_nt<true, 0><<<dim3(16, 16, 8), 256, 0, stream>>>(C2 + 256, C2, S, nullptr, 512, 512, 2048, 16, 4096L * 512,
                                                          4096L * 512, 2048L * 2048);

    // column softmax (over i, per column j)
    softmax_stats<<<dim3(32, 8), 256, 0, stream>>>(S, mSt, rSt);
    apply_softmax<<<16384, 256, 0, stream>>>(S, mSt, rSt);

    // Y2[i][c] = sum_j P[i][j] * Gv[c][j]; Gv = Gc viewed with ld 2048; Y2 reuses C2 (dead)
    gemm_nt<false, 0><<<dim3(16, 4, 8), 256, 0, stream>>>(S, Gc, Y2, nullptr, 2048, 2048, 512, 64, 2048L * 2048,
                                                          1048576L, 2048L * 512);

    // Y2 -> Yt (stride-2 de-interleave of the channel view); Yt reuses A_region (S dead)
    interleave_y<<<4096, 256, 0, stream>>>(Y2, Yt);

    // mask conv + residual: out[oc][p] = x[oc][p] + sum_ic Wm[oc][ic]*Yt[p][ic]
    gemm_nt<false, 1><<<dim3(4, 32, 8), 256, 0, stream>>>(Wm, Yt, out, x, 256, 256, 4096, 8, 0, 4096L * 256,
                                                          512L * 4096);
}

// Round 3
// 367.326 us; speedup vs baseline: 1.0311x; 1.0311x over previous
//
#include <hip/hip_runtime.h>
#include <cstdint>
#include <cstddef>

// ---------- fp16 helpers ----------
typedef __attribute__((ext_vector_type(8))) _Float16 half8;
typedef __attribute__((ext_vector_type(4))) float floatx4;

static __device__ __forceinline__ uint16_t f2h(float f) {
    _Float16 h = (_Float16)f;
    uint16_t u;
    __builtin_memcpy(&u, &h, 2);
    return u;
}
static __device__ __forceinline__ float h2f(uint16_t u) {
    _Float16 h;
    __builtin_memcpy(&h, &u, 2);
    return (float)h;
}

// async global->LDS, 16B per lane. LDS dest must be wave-uniform base + lane*16,
// which our staging layout satisfies exactly (chunk index = wave*64 + lane + s*256).
static __device__ __forceinline__ void g2lds16(const void* g, void* l) {
    __builtin_amdgcn_global_load_lds((__attribute__((address_space(1))) void*)g,
                                     (__attribute__((address_space(3))) void*)l, 16, 0, 0);
}

// ---------- fp32 -> fp16 convert (weights) ----------
__global__ void cvt_f32_f16(const float* __restrict__ in, uint16_t* __restrict__ out, int n) {
    int i = blockIdx.x * blockDim.x + threadIdx.x;
    int base = i * 4;
    if (base < n) {
        float4 v = *(const float4*)(in + base);
        ushort4 u = make_ushort4(f2h(v.x), f2h(v.y), f2h(v.z), f2h(v.w));
        *(ushort4*)(out + base) = u;
    }
}

// ---------- transpose x: (b,512,4096) f32 -> Xt (b,4096,512) f16 ----------
__global__ __launch_bounds__(256) void transpose_x(const float* __restrict__ x, uint16_t* __restrict__ xt) {
    __shared__ uint16_t tile[64][66];
    int b = blockIdx.z, p0 = blockIdx.x * 64, c0 = blockIdx.y * 64;
    int t0 = threadIdx.x & 63, t1 = threadIdx.x >> 6;
    const float* xb = x + ((long)b * 512 + c0) * 4096 + p0;
#pragma unroll
    for (int r = 0; r < 16; ++r) {
        int cc = t1 * 16 + r;
        tile[cc][t0] = f2h(xb[(long)cc * 4096 + t0]);
    }
    __syncthreads();
    uint16_t* xtb = xt + ((long)b * 4096 + p0) * 512 + c0;
#pragma unroll
    for (int r = 0; r < 16; ++r) {
        int pp = t1 * 16 + r;
        xtb[(long)pp * 512 + t0] = tile[t0][pp];
    }
}

// ---------- NT GEMM: C[m][n] = sum_k A[m][k]*B[n][k], fp16 in ----------
// 128x128 tile, BK=32, 4 waves each 64x64 (4x4 of 16x16x32 MFMA).
// KHALF: for k>=256 both A and B row bases shift by 2048 rows, k -= 256 (channel-view split).
// EPI: 0 = fp16 C[m][n]; 1 = fp32 C[m][n] + residual;
//      3 = mixed conv epilogue: n0<512 -> fp16 C[m][n] (C2), n0>=512 -> fp16 transposed Cout2[n-512][m] (Gc)
// SWAP: m0 from blockIdx.y, n0 from blockIdx.x (consecutive blocks share the A-tile -> L2 reuse)
template <bool KHALF, int EPI, bool SWAP>
__global__ __launch_bounds__(256) void gemm_nt(const uint16_t* __restrict__ A, const uint16_t* __restrict__ B,
                                               void* __restrict__ Cout, const float* __restrict__ resid,
                                               int lda, int ldb, int ldc, int nK,
                                               long aBatch, long bBatch, long cBatch,
                                               void* __restrict__ Cout2, int ldc2, long c2Batch) {
    __shared__ uint16_t Al[128 * 32];
    __shared__ uint16_t Bl[128 * 32];
    const int b = blockIdx.z;
    const uint16_t* Ab = A + (long)b * aBatch;
    const uint16_t* Bb = B + (long)b * bBatch;
    const int m0 = (SWAP ? blockIdx.y : blockIdx.x) * 128;
    const int n0 = (SWAP ? blockIdx.x : blockIdx.y) * 128;
    const int tid = threadIdx.x;
    const int lane = tid & 63, wave = tid >> 6;
    const int ln = lane & 15, q = lane >> 4;
    const int wm = (wave & 1) * 64, wn = (wave >> 1) * 64;

    floatx4 acc[4][4];
#pragma unroll
    for (int i = 0; i < 4; ++i)
#pragma unroll
        for (int j = 0; j < 4; ++j) acc[i][j] = (floatx4){0.f, 0.f, 0.f, 0.f};

    for (int kt = 0; kt < nK; ++kt) {
        int k0 = kt * 32;
        int keff = k0;
        long roff = 0;
        if (KHALF && k0 >= 256) { keff = k0 - 256; roff = 2048; }
#pragma unroll
        for (int s = 0; s < 2; ++s) {
            int c = tid + s * 256;           // 512 chunks of 16B per operand
            int row = c >> 2, kq = (c & 3) * 8;
            g2lds16(Ab + ((long)(m0 + row) + roff) * lda + keff + kq, &Al[c * 8]);
            g2lds16(Bb + ((long)(n0 + row) + roff) * ldb + keff + kq, &Bl[c * 8]);
        }
        __syncthreads();
        half8 af[4], bfr[4];
#pragma unroll
        for (int mt = 0; mt < 4; ++mt) af[mt] = *(const half8*)&Al[(wm + mt * 16 + ln) * 32 + q * 8];
#pragma unroll
        for (int nt = 0; nt < 4; ++nt) bfr[nt] = *(const half8*)&Bl[(wn + nt * 16 + ln) * 32 + q * 8];
#pragma unroll
        for (int mt = 0; mt < 4; ++mt)
#pragma unroll
            for (int nt = 0; nt < 4; ++nt)
                acc[mt][nt] = __builtin_amdgcn_mfma_f32_16x16x32_f16(af[mt], bfr[nt], acc[mt][nt], 0, 0, 0);
        __syncthreads();
    }

    // C/D layout (verified m89): col = lane&15, row = (lane>>4)*4 + reg
    if (EPI == 0 || (EPI == 3 && n0 < 512)) {
        uint16_t* C = (uint16_t*)Cout + (long)b * cBatch;
#pragma unroll
        for (int mt = 0; mt < 4; ++mt)
#pragma unroll
            for (int r = 0; r < 4; ++r) {
                int gm = m0 + wm + mt * 16 + q * 4 + r;
#pragma unroll
                for (int nt = 0; nt < 4; ++nt) {
                    int gn = n0 + wn + nt * 16 + ln;
                    C[(long)gm * ldc + gn] = f2h(acc[mt][nt][r]);
                }
            }
    } else if (EPI == 1) {
        float* C = (float*)Cout + (long)b * cBatch;
        const float* X = resid + (long)b * cBatch;
#pragma unroll
        for (int mt = 0; mt < 4; ++mt)
#pragma unroll
            for (int r = 0; r < 4; ++r) {
                int gm = m0 + wm + mt * 16 + q * 4 + r;
#pragma unroll
                for (int nt = 0; nt < 4; ++nt) {
                    int gn = n0 + wn + nt * 16 + ln;
                    long idx = (long)gm * ldc + gn;
                    C[idx] = acc[mt][nt][r] + X[idx];
                }
            }
    } else {
        // transposed epilogue into Cout2: row = gn - 512, 4 contiguous m per lane -> ushort4 stores
        uint16_t* C = (uint16_t*)Cout2 + (long)b * c2Batch;
#pragma unroll
        for (int nt = 0; nt < 4; ++nt) {
            int gn2 = n0 - 512 + wn + nt * 16 + ln;
#pragma unroll
            for (int mt = 0; mt < 4; ++mt) {
                int gmB = m0 + wm + mt * 16 + q * 4;
                ushort4 u = make_ushort4(f2h(acc[mt][nt][0]), f2h(acc[mt][nt][1]), f2h(acc[mt][nt][2]),
                                         f2h(acc[mt][nt][3]));
                *(ushort4*)&C[(long)gn2 * ldc2 + gmB] = u;
            }
        }
    }
}

// ---------- fused column softmax: per (b, 64-col block) compute m,l over i then rewrite in place ----------
// grid (32, 8), block 512 = 16 row-strips x 32 uint-lanes (64 columns). Phase 2 runs in reverse
// row order so the re-read hits the freshest L2 lines.
__global__ __launch_bounds__(512) void softmax_fused(uint16_t* __restrict__ S) {
    const int b = blockIdx.y;
    const int jp = threadIdx.x & 31;   // uint column-pair lane
    const int s = threadIdx.x >> 5;    // row strip 0..15
    const long cb = (long)blockIdx.x * 32 + jp;  // uint column index (2 fp16 cols)
    uint32_t* Sp = (uint32_t*)S + (long)b * 2048 * 1024 + cb;
    const int i0 = s * 128, i1 = i0 + 128;

    float ma = -1e30f, la = 0.f, mb = -1e30f, lb = 0.f;
    for (int i = i0; i < i1; ++i) {
        uint32_t u = Sp[(long)i * 1024];
        float va = h2f((uint16_t)(u & 0xffffu));
        float vb = h2f((uint16_t)(u >> 16));
        float na = fmaxf(ma, va);
        la = la * __expf(ma - na) + __expf(va - na);
        ma = na;
        float nb = fmaxf(mb, vb);
        lb = lb * __expf(mb - nb) + __expf(vb - nb);
        mb = nb;
    }
    __shared__ float sm[16][64], sl[16][64], fM[64], fR[64];
    sm[s][jp * 2] = ma;
    sl[s][jp * 2] = la;
    sm[s][jp * 2 + 1] = mb;
    sl[s][jp * 2 + 1] = lb;
    __syncthreads();
    if (s < 2) {
        int col = jp * 2 + s;  // 64 threads cover 64 columns
        float M = sm[0][col];
#pragma unroll
        for (int k = 1; k < 16; ++k) M = fmaxf(M, sm[k][col]);
        float L = 0.f;
#pragma unroll
        for (int k = 0; k < 16; ++k) L += sl[k][col] * __expf(sm[k][col] - M);
        fM[col] = M;
        fR[col] = 1.f / L;
    }
    __syncthreads();
    float Ma = fM[jp * 2], Ra = fR[jp * 2];
    float Mb = fM[jp * 2 + 1], Rb = fR[jp * 2 + 1];
    for (int i = i1 - 1; i >= i0; --i) {
        uint32_t u = Sp[(long)i * 1024];
        float va = h2f((uint16_t)(u & 0xffffu));
        float vb = h2f((uint16_t)(u >> 16));
        float pa = __expf(va - Ma) * Ra;
        float pb = __expf(vb - Mb) * Rb;
        Sp[(long)i * 1024] = (uint32_t)f2h(pa) | ((uint32_t)f2h(pb) << 16);
    }
}

// ---------- de-interleave: Yt[b][p][ic] = Y2[b][p%2048][2*ic + p/2048] ----------
__global__ void interleave_y(const uint16_t* __restrict__ y2, uint16_t* __restrict__ yt) {
    long t = (long)blockIdx.x * 256 + threadIdx.x;  // 1,048,576 threads, 8 out elems each
    long obase = t * 8;
    int ic0 = (int)(obase & 255);
    long prow = obase >> 8;  // b*4096 + p
    int p = (int)(prow & 4095);
    int b = (int)(prow >> 12);
    int i = p & 2047, h = p >> 11;
    const uint16_t* src = y2 + ((long)b * 2048 + i) * 512 + 2 * ic0;
    uint4 v0 = *(const uint4*)src;
    uint4 v1 = *(const uint4*)(src + 8);
    uint32_t* a = (uint32_t*)&v0;
    uint32_t* c = (uint32_t*)&v1;
    uint32_t o[4];
    if (h == 0) {
        o[0] = (a[0] & 0xffffu) | (a[1] << 16);
        o[1] = (a[2] & 0xffffu) | (a[3] << 16);
        o[2] = (c[0] & 0xffffu) | (c[1] << 16);
        o[3] = (c[2] & 0xffffu) | (c[3] << 16);
    } else {
        o[0] = (a[0] >> 16) | (a[1] & 0xffff0000u);
        o[1] = (a[2] >> 16) | (a[3] & 0xffff0000u);
        o[2] = (c[0] >> 16) | (c[1] & 0xffff0000u);
        o[3] = (c[2] >> 16) | (c[3] & 0xffff0000u);
    }
    *(uint4*)(yt + obase) = *(uint4*)o;
}

// ---------- launch ----------
// ws layout (total 118,620,160 B = 113.1 MB; fits ws_size — round-0's 202.5 MB overflowed):
//   W3   @ 0         768x512 f16 (phi rows 0-255, theta 256-511, g 512-767)
//   Wm   @ 786432    512x256 f16
//   (1 MB pad/unused)
//   A_region @ 1179648  (64 MB): Xt (32 MB) -> S (64 MB) -> Yt (16 MB)
//   B_region @ 68288512 (48 MB): C2 (32 MB) @ +0 -> Y2 (16 MB) @ +0 ; Gc (16 MB) @ +32MB
extern "C" void kernel_launch(void* const* d_in, const int* in_sizes, int n_in, void* d_out, int out_size, void* d_ws,
                              size_t ws_size, hipStream_t stream) {
    const float* x = (const float*)d_in[0];
    const float* wphi = (const float*)d_in[1];
    const float* wtheta = (const float*)d_in[2];
    const float* wg = (const float*)d_in[3];
    const float* wmask = (const float*)d_in[4];
    float* out = (float*)d_out;
    char* ws = (char*)d_ws;

    uint16_t* W3 = (uint16_t*)(ws + 0);
    uint16_t* Wm = (uint16_t*)(ws + 786432);
    char* A_region = ws + 1179648;
    char* B_region = ws + 68288512;
    uint16_t* Xt = (uint16_t*)A_region;
    uint16_t* S = (uint16_t*)A_region;
    uint16_t* Yt = (uint16_t*)A_region;
    uint16_t* C2 = (uint16_t*)B_region;
    uint16_t* Y2 = (uint16_t*)B_region;
    uint16_t* Gc = (uint16_t*)(B_region + 33554432);

    // weights -> fp16
    cvt_f32_f16<<<128, 256, 0, stream>>>(wphi, W3, 131072);
    cvt_f32_f16<<<128, 256, 0, stream>>>(wtheta, W3 + 131072, 131072);
    cvt_f32_f16<<<128, 256, 0, stream>>>(wg, W3 + 262144, 131072);
    cvt_f32_f16<<<128, 256, 0, stream>>>(wmask, Wm, 131072);

    // x -> Xt (pixel-major fp16)
    transpose_x<<<dim3(64, 8, 8), 256, 0, stream>>>(x, Xt);

    // fused 3-conv: n=768; n0<512 -> C2[b][p][{phi|theta}], n0>=512 -> Gc[b][o][p] transposed
    gemm_nt<false, 3, false><<<dim3(32, 6, 8), 256, 0, stream>>>(Xt, W3, C2, nullptr, 512, 512, 512, 16, 4096L * 512,
                                                                 0, 4096L * 512, Gc, 4096, 256L * 4096);

    // scores: S[i][j] with k-half row shift (channel-view split); overwrites Xt (dead)
    gemm_nt<true, 0, false><<<dim3(16, 16, 8), 256, 0, stream>>>(C2 + 256, C2, S, nullptr, 512, 512, 2048, 16,
                                                                 4096L * 512, 4096L * 512, 2048L * 2048, nullptr, 0, 0);

    // fused column softmax (stats + in-place exp/scale)
    softmax_fused<<<dim3(32, 8), 512, 0, stream>>>(S);

    // Y2[i][c] = sum_j P[i][j] * Gc[c][j]; SWAP grid so consecutive blocks share the P-tile (L2 reuse)
    gemm_nt<false, 0, true><<<dim3(4, 16, 8), 256, 0, stream>>>(S, Gc, Y2, nullptr, 2048, 2048, 512, 64, 2048L * 2048,
                                                                1048576L, 2048L * 512, nullptr, 0, 0);

    // Y2 -> Yt (stride-2 de-interleave of the channel view); Yt reuses A_region (S dead)
    interleave_y<<<4096, 256, 0, stream>>>(Y2, Yt);

    // mask conv + residual: out[oc][p] = x[oc][p] + sum_ic Wm[oc][ic]*Yt[p][ic]
    gemm_nt<false, 1, false><<<dim3(4, 32, 8), 256, 0, stream>>>(Wm, Yt, out, x, 256, 256, 4096, 8, 0, 4096L * 256,
                                                                 512L * 4096, nullptr, 0, 0);
}

// Round 4
// 346.613 us; speedup vs baseline: 1.0927x; 1.0598x over previous
//
#include <hip/hip_runtime.h>
#include <cstdint>
#include <cstddef>

// ---------- fp16 helpers ----------
typedef __attribute__((ext_vector_type(8))) _Float16 half8;
typedef __attribute__((ext_vector_type(4))) float floatx4;

static __device__ __forceinline__ uint16_t f2h(float f) {
    _Float16 h = (_Float16)f;
    uint16_t u;
    __builtin_memcpy(&u, &h, 2);
    return u;
}
static __device__ __forceinline__ float h2f(uint16_t u) {
    _Float16 h;
    __builtin_memcpy(&h, &u, 2);
    return (float)h;
}

// async global->LDS, 16B per lane (dest = wave-uniform base + lane*16 — our chunk layout).
static __device__ __forceinline__ void g2lds16(const void* g, void* l) {
    __builtin_amdgcn_global_load_lds((__attribute__((address_space(1))) void*)g,
                                     (__attribute__((address_space(3))) void*)l, 16, 0, 0);
}

// ---------- weights fp32->fp16 (+ zero the L accumulator), one launch ----------
__global__ void cvt_weights(const float* __restrict__ wphi, const float* __restrict__ wtheta,
                            const float* __restrict__ wg, const float* __restrict__ wmask,
                            uint16_t* __restrict__ W3, uint16_t* __restrict__ Wm, float* __restrict__ L) {
    int seg = blockIdx.y;
    int i = blockIdx.x * 256 + threadIdx.x;
    if (seg == 4) {
        if (i < 16384) L[i] = 0.f;
        return;
    }
    const float* src = seg == 0 ? wphi : seg == 1 ? wtheta : seg == 2 ? wg : wmask;
    uint16_t* dst = seg < 3 ? W3 + seg * 131072 : Wm;
    int base = i * 4;  // grid.x=128 -> base < 131072 exactly
    float4 v = *(const float4*)(src + base);
    *(ushort4*)(dst + base) = make_ushort4(f2h(v.x), f2h(v.y), f2h(v.z), f2h(v.w));
}

// ---------- R = 1/L ----------
__global__ void recip_f32(const float* __restrict__ l, float* __restrict__ r) {
    int i = blockIdx.x * 256 + threadIdx.x;
    r[i] = 1.f / l[i];
}

// ---------- transpose x: (b,512,4096) f32 -> Xt (b,4096,512) f16 ----------
__global__ __launch_bounds__(256) void transpose_x(const float* __restrict__ x, uint16_t* __restrict__ xt) {
    __shared__ uint16_t tile[64][66];
    int b = blockIdx.z, p0 = blockIdx.x * 64, c0 = blockIdx.y * 64;
    int t0 = threadIdx.x & 63, t1 = threadIdx.x >> 6;
    const float* xb = x + ((long)b * 512 + c0) * 4096 + p0;
#pragma unroll
    for (int r = 0; r < 16; ++r) {
        int cc = t1 * 16 + r;
        tile[cc][t0] = f2h(xb[(long)cc * 4096 + t0]);
    }
    __syncthreads();
    uint16_t* xtb = xt + ((long)b * 4096 + p0) * 512 + c0;
#pragma unroll
    for (int r = 0; r < 16; ++r) {
        int pp = t1 * 16 + r;
        xtb[(long)pp * 512 + t0] = tile[t0][pp];
    }
}

// ---------- NT GEMM: C[m][n] = sum_k A[m][k]*B[n][k], fp16 in ----------
// 128x128 tile, BK=32, 4 waves each 64x64 (4x4 of 16x16x32 MFMA).
// KHALF: for k>=256 both A and B row bases shift by 2048 rows, k -= 256 (channel-view split).
// EPI: 0 = fp16 C[m][n]; 1 = fp32 C[m][n] + residual;
//      3 = mixed conv epilogue (n0<512 -> C2[m][n]; n0>=512 -> transposed Gc[n-512][m]);
//      4 = fp16 C[m][n] + atomic column sums L[j] += exp(Sh-12)  (scores)
// SWAP: m0 from blockIdx.y, n0 from blockIdx.x (consecutive blocks share the A-tile -> L2 reuse)
// ASOFT: A-staging register path applies exp(Sh-12)*R[j]  (PV; A=S, k index = j)
// BGATHER: B-staging register path gathers the channel-view de-interleave from Y2 (mask GEMM)
template <bool KHALF, int EPI, bool SWAP, bool ASOFT, bool BGATHER>
__global__ __launch_bounds__(256) void gemm_nt(const uint16_t* __restrict__ A, const uint16_t* __restrict__ B,
                                               void* __restrict__ Cout, const float* __restrict__ resid,
                                               int lda, int ldb, int ldc, int nK,
                                               long aBatch, long bBatch, long cBatch,
                                               void* __restrict__ Cout2, int ldc2, long c2Batch,
                                               float* __restrict__ Lsum, const float* __restrict__ Rvec) {
    __shared__ uint16_t Al[128 * 32];
    __shared__ uint16_t Bl[128 * 32];
    const int b = blockIdx.z;
    const uint16_t* Ab = A + (long)b * aBatch;
    const uint16_t* Bb = B + (long)b * bBatch;
    const int m0 = (SWAP ? blockIdx.y : blockIdx.x) * 128;
    const int n0 = (SWAP ? blockIdx.x : blockIdx.y) * 128;
    const int tid = threadIdx.x;
    const int lane = tid & 63, wave = tid >> 6;
    const int ln = lane & 15, q = lane >> 4;
    const int wm = (wave & 1) * 64, wn = (wave >> 1) * 64;

    floatx4 acc[4][4];
#pragma unroll
    for (int i = 0; i < 4; ++i)
#pragma unroll
        for (int j = 0; j < 4; ++j) acc[i][j] = (floatx4){0.f, 0.f, 0.f, 0.f};

    for (int kt = 0; kt < nK; ++kt) {
        int k0 = kt * 32;
        int keff = k0;
        long roff = 0;
        if (KHALF && k0 >= 256) { keff = k0 - 256; roff = 2048; }
#pragma unroll
        for (int s = 0; s < 2; ++s) {
            int c = tid + s * 256;  // 512 chunks of 16B per operand
            int row = c >> 2, kq = (c & 3) * 8;
            // ---- A operand ----
            if (ASOFT) {
                uint4 v = *(const uint4*)(Ab + (long)(m0 + row) * lda + keff + kq);
                const float* Rp = Rvec + (long)b * 2048 + keff + kq;
                float4 ra = *(const float4*)Rp;
                float4 rb = *(const float4*)(Rp + 4);
                float rr[8] = {ra.x, ra.y, ra.z, ra.w, rb.x, rb.y, rb.z, rb.w};
                uint32_t* pv = (uint32_t*)&v;
                uint32_t o[4];
#pragma unroll
                for (int e = 0; e < 4; ++e) {
                    float va = h2f((uint16_t)(pv[e] & 0xffffu));
                    float vb = h2f((uint16_t)(pv[e] >> 16));
                    float pa = __expf(va - 12.f) * rr[2 * e];
                    float pb = __expf(vb - 12.f) * rr[2 * e + 1];
                    o[e] = (uint32_t)f2h(pa) | ((uint32_t)f2h(pb) << 16);
                }
                *(uint4*)&Al[c * 8] = *(uint4*)o;
            } else {
                g2lds16(Ab + ((long)(m0 + row) + roff) * lda + keff + kq, &Al[c * 8]);
            }
            // ---- B operand ----
            if (BGATHER) {
                int pg = n0 + row;
                int ii = pg & 2047, hh = pg >> 11;
                const uint16_t* src = Bb + (long)ii * 512 + 2 * (keff + kq);
                uint4 v0 = *(const uint4*)src;
                uint4 v1 = *(const uint4*)(src + 8);
                uint32_t* a = (uint32_t*)&v0;
                uint32_t* cc = (uint32_t*)&v1;
                uint32_t o[4];
                if (hh == 0) {
                    o[0] = (a[0] & 0xffffu) | (a[1] << 16);
                    o[1] = (a[2] & 0xffffu) | (a[3] << 16);
                    o[2] = (cc[0] & 0xffffu) | (cc[1] << 16);
                    o[3] = (cc[2] & 0xffffu) | (cc[3] << 16);
                } else {
                    o[0] = (a[0] >> 16) | (a[1] & 0xffff0000u);
                    o[1] = (a[2] >> 16) | (a[3] & 0xffff0000u);
                    o[2] = (cc[0] >> 16) | (cc[1] & 0xffff0000u);
                    o[3] = (cc[2] >> 16) | (cc[3] & 0xffff0000u);
                }
                *(uint4*)&Bl[c * 8] = *(uint4*)o;
            } else {
                g2lds16(Bb + ((long)(n0 + row) + roff) * ldb + keff + kq, &Bl[c * 8]);
            }
        }
        __syncthreads();
        half8 af[4], bfr[4];
#pragma unroll
        for (int mt = 0; mt < 4; ++mt) af[mt] = *(const half8*)&Al[(wm + mt * 16 + ln) * 32 + q * 8];
#pragma unroll
        for (int nt = 0; nt < 4; ++nt) bfr[nt] = *(const half8*)&Bl[(wn + nt * 16 + ln) * 32 + q * 8];
#pragma unroll
        for (int mt = 0; mt < 4; ++mt)
#pragma unroll
            for (int nt = 0; nt < 4; ++nt)
                acc[mt][nt] = __builtin_amdgcn_mfma_f32_16x16x32_f16(af[mt], bfr[nt], acc[mt][nt], 0, 0, 0);
        __syncthreads();
    }

    // C/D layout (verified m89): col = lane&15, row = (lane>>4)*4 + reg
    if (EPI == 0 || (EPI == 3 && n0 < 512)) {
        uint16_t* C = (uint16_t*)Cout + (long)b * cBatch;
#pragma unroll
        for (int mt = 0; mt < 4; ++mt)
#pragma unroll
            for (int r = 0; r < 4; ++r) {
                int gm = m0 + wm + mt * 16 + q * 4 + r;
#pragma unroll
                for (int nt = 0; nt < 4; ++nt) {
                    int gn = n0 + wn + nt * 16 + ln;
                    C[(long)gm * ldc + gn] = f2h(acc[mt][nt][r]);
                }
            }
    } else if (EPI == 4) {
        uint16_t* C = (uint16_t*)Cout + (long)b * cBatch;
        float cs[4] = {0.f, 0.f, 0.f, 0.f};
#pragma unroll
        for (int mt = 0; mt < 4; ++mt)
#pragma unroll
            for (int r = 0; r < 4; ++r) {
                int gm = m0 + wm + mt * 16 + q * 4 + r;
#pragma unroll
                for (int nt = 0; nt < 4; ++nt) {
                    int gn = n0 + wn + nt * 16 + ln;
                    uint16_t hh = f2h(acc[mt][nt][r]);
                    C[(long)gm * ldc + gn] = hh;
                    cs[nt] += __expf(h2f(hh) - 12.f);
                }
            }
#pragma unroll
        for (int nt = 0; nt < 4; ++nt) {
            float s = cs[nt];
            s += __shfl_xor(s, 16);
            s += __shfl_xor(s, 32);
            if (q == 0) atomicAdd(&Lsum[(long)b * 2048 + n0 + wn + nt * 16 + ln], s);
        }
    } else if (EPI == 1) {
        float* C = (float*)Cout + (long)b * cBatch;
        const float* X = resid + (long)b * cBatch;
#pragma unroll
        for (int mt = 0; mt < 4; ++mt)
#pragma unroll
            for (int r = 0; r < 4; ++r) {
                int gm = m0 + wm + mt * 16 + q * 4 + r;
#pragma unroll
                for (int nt = 0; nt < 4; ++nt) {
                    int gn = n0 + wn + nt * 16 + ln;
                    long idx = (long)gm * ldc + gn;
                    C[idx] = acc[mt][nt][r] + X[idx];
                }
            }
    } else {
        // transposed epilogue into Cout2: row = gn - 512, 4 contiguous m per lane -> ushort4 stores
        uint16_t* C = (uint16_t*)Cout2 + (long)b * c2Batch;
#pragma unroll
        for (int nt = 0; nt < 4; ++nt) {
            int gn2 = n0 - 512 + wn + nt * 16 + ln;
#pragma unroll
            for (int mt = 0; mt < 4; ++mt) {
                int gmB = m0 + wm + mt * 16 + q * 4;
                ushort4 u = make_ushort4(f2h(acc[mt][nt][0]), f2h(acc[mt][nt][1]), f2h(acc[mt][nt][2]),
                                         f2h(acc[mt][nt][3]));
                *(ushort4*)&C[(long)gn2 * ldc2 + gmB] = u;
            }
        }
    }
}

// ---------- launch ----------
// ws layout (total 116,843,520 B):
//   W3 @ 0 (768x512 f16: phi|theta|g) ; Wm @ 786432 (512x256 f16)
//   L  @ 1048576 (8x2048 f32) ; R @ 1114112 (8x2048 f32)
//   A_region @ 1179648  (64 MB): Xt (32 MB) -> S (64 MB)
//   B_region @ 68288512 (48 MB): C2 (32 MB) -> Y2 (16 MB) @ +0 ; Gc (16 MB) @ +32MB
// Softmax: P = exp(S-12)*R[j]; L[j] accumulated by the scores epilogue (atomics),
// exp applied in the PV A-staging register path. No separate softmax/interleave passes.
extern "C" void kernel_launch(void* const* d_in, const int* in_sizes, int n_in, void* d_out, int out_size, void* d_ws,
                              size_t ws_size, hipStream_t stream) {
    const float* x = (const float*)d_in[0];
    const float* wphi = (const float*)d_in[1];
    const float* wtheta = (const float*)d_in[2];
    const float* wg = (const float*)d_in[3];
    const float* wmask = (const float*)d_in[4];
    float* out = (float*)d_out;
    char* ws = (char*)d_ws;

    uint16_t* W3 = (uint16_t*)(ws + 0);
    uint16_t* Wm = (uint16_t*)(ws + 786432);
    float* L = (float*)(ws + 1048576);
    float* R = (float*)(ws + 1114112);
    char* A_region = ws + 1179648;
    char* B_region = ws + 68288512;
    uint16_t* Xt = (uint16_t*)A_region;
    uint16_t* S = (uint16_t*)A_region;
    uint16_t* C2 = (uint16_t*)B_region;
    uint16_t* Y2 = (uint16_t*)B_region;
    uint16_t* Gc = (uint16_t*)(B_region + 33554432);

    // weights -> fp16, L zeroed (one launch)
    cvt_weights<<<dim3(128, 5), 256, 0, stream>>>(wphi, wtheta, wg, wmask, W3, Wm, L);

    // x -> Xt (pixel-major fp16)
    transpose_x<<<dim3(64, 8, 8), 256, 0, stream>>>(x, Xt);

    // fused 3-conv: n=768; n0<512 -> C2[b][p][{phi|theta}], n0>=512 -> Gc[b][o][p] transposed
    gemm_nt<false, 3, false, false, false><<<dim3(32, 6, 8), 256, 0, stream>>>(
        Xt, W3, C2, nullptr, 512, 512, 512, 16, 4096L * 512, 0, 4096L * 512, Gc, 4096, 256L * 4096, nullptr, nullptr);

    // scores: S[i][j] (k-half row shift) + column sums L[j] of exp(S-12); overwrites Xt (dead)
    gemm_nt<true, 4, false, false, false><<<dim3(16, 16, 8), 256, 0, stream>>>(
        C2 + 256, C2, S, nullptr, 512, 512, 2048, 16, 4096L * 512, 4096L * 512, 2048L * 2048, nullptr, 0, 0, L,
        nullptr);

    // R = 1/L
    recip_f32<<<64, 256, 0, stream>>>(L, R);

    // PV: Y2[i][c] = sum_j (exp(S[i][j]-12)*R[j]) * Gv[c][j]; exp*R applied in A-staging;
    // SWAP grid so consecutive blocks share the A-tile (L2 reuse). Y2 reuses C2 (dead).
    gemm_nt<false, 0, true, true, false><<<dim3(4, 16, 8), 256, 0, stream>>>(
        S, Gc, Y2, nullptr, 2048, 2048, 512, 64, 2048L * 2048, 1048576L, 2048L * 512, nullptr, 0, 0, nullptr, R);

    // mask conv + residual, de-interleave folded into B-staging gather from Y2:
    // out[oc][p] = x[oc][p] + sum_ic Wm[oc][ic] * Y2[p&2047][2*ic + (p>>11)]
    gemm_nt<false, 1, false, false, true><<<dim3(4, 32, 8), 256, 0, stream>>>(
        Wm, Y2, out, x, 256, 512, 4096, 8, 0, 1048576L, 512L * 4096, nullptr, 0, 0, nullptr, nullptr);
}

// Round 5
// 319.194 us; speedup vs baseline: 1.1865x; 1.0859x over previous
//
#include <hip/hip_runtime.h>
#include <cstdint>
#include <cstddef>

// ---------- fp16/bf16 helpers ----------
typedef __attribute__((ext_vector_type(8))) _Float16 half8;
typedef __attribute__((ext_vector_type(8))) short short8;
typedef __attribute__((ext_vector_type(4))) float floatx4;

static __device__ __forceinline__ uint16_t f2h(float f) {
    _Float16 h = (_Float16)f;
    uint16_t u;
    __builtin_memcpy(&u, &h, 2);
    return u;
}
static __device__ __forceinline__ float h2f(uint16_t u) {
    _Float16 h;
    __builtin_memcpy(&h, &u, 2);
    return (float)h;
}
static __device__ __forceinline__ uint16_t f2bf(float f) {
    uint32_t u;
    __builtin_memcpy(&u, &f, 4);
    u += 0x7fffu + ((u >> 16) & 1u);  // round-to-nearest-even
    return (uint16_t)(u >> 16);
}

// async global->LDS, 16B per lane (dest = wave-uniform base + lane*16 — our chunk layout).
static __device__ __forceinline__ void g2lds16(const void* g, void* l) {
    __builtin_amdgcn_global_load_lds((__attribute__((address_space(1))) void*)g,
                                     (__attribute__((address_space(3))) void*)l, 16, 0, 0);
}

// ---------- weights fp32->fp16 (+ zero the L accumulator), one launch ----------
__global__ void cvt_weights(const float* __restrict__ wphi, const float* __restrict__ wtheta,
                            const float* __restrict__ wg, const float* __restrict__ wmask,
                            uint16_t* __restrict__ W3, uint16_t* __restrict__ Wm, float* __restrict__ L) {
    int seg = blockIdx.y;
    int i = blockIdx.x * 256 + threadIdx.x;
    if (seg == 4) {
        if (i < 16384) L[i] = 0.f;
        return;
    }
    const float* src = seg == 0 ? wphi : seg == 1 ? wtheta : seg == 2 ? wg : wmask;
    uint16_t* dst = seg < 3 ? W3 + seg * 131072 : Wm;
    int base = i * 4;  // grid.x=128 -> base < 131072 exactly
    float4 v = *(const float4*)(src + base);
    *(ushort4*)(dst + base) = make_ushort4(f2h(v.x), f2h(v.y), f2h(v.z), f2h(v.w));
}

// ---------- transpose x: (b,512,4096) f32 -> Xt (b,4096,512) f16 ----------
__global__ __launch_bounds__(256) void transpose_x(const float* __restrict__ x, uint16_t* __restrict__ xt) {
    __shared__ uint16_t tile[64][66];
    int b = blockIdx.z, p0 = blockIdx.x * 64, c0 = blockIdx.y * 64;
    int t0 = threadIdx.x & 63, t1 = threadIdx.x >> 6;
    const float* xb = x + ((long)b * 512 + c0) * 4096 + p0;
#pragma unroll
    for (int r = 0; r < 16; ++r) {
        int cc = t1 * 16 + r;
        tile[cc][t0] = f2h(xb[(long)cc * 4096 + t0]);
    }
    __syncthreads();
    uint16_t* xtb = xt + ((long)b * 4096 + p0) * 512 + c0;
#pragma unroll
    for (int r = 0; r < 16; ++r) {
        int pp = t1 * 16 + r;
        xtb[(long)pp * 512 + t0] = tile[t0][pp];
    }
}

// ---------- scale+normalize g: Gc (fp16) -> Gc (bf16), element f *= 1/L[f & 2047] ----------
// Gc viewed flat per batch: [512 rows][2048 j]; the PV k-index j = flat & 2047.
__global__ void scale_g(uint16_t* __restrict__ gc, const float* __restrict__ L) {
    long t = (long)blockIdx.x * 256 + threadIdx.x;  // 1,048,576 threads, 8 elems each
    long base = t * 8;
    int j0 = (int)(base & 2047);
    int b = (int)(base >> 20);  // 256*4096 elems per batch
    const float* Lp = L + (long)b * 2048 + j0;
    float4 l0 = *(const float4*)Lp;
    float4 l1 = *(const float4*)(Lp + 4);
    float rr[8] = {1.f / l0.x, 1.f / l0.y, 1.f / l0.z, 1.f / l0.w, 1.f / l1.x, 1.f / l1.y, 1.f / l1.z, 1.f / l1.w};
    uint4 v = *(uint4*)(gc + base);
    uint32_t* pv = (uint32_t*)&v;
    uint32_t o[4];
#pragma unroll
    for (int e = 0; e < 4; ++e) {
        float a = h2f((uint16_t)(pv[e] & 0xffffu)) * rr[2 * e];
        float c = h2f((uint16_t)(pv[e] >> 16)) * rr[2 * e + 1];
        o[e] = (uint32_t)f2bf(a) | ((uint32_t)f2bf(c) << 16);
    }
    *(uint4*)(gc + base) = *(uint4*)o;
}

// ---------- NT GEMM: C[m][n] = sum_k A[m][k]*B[n][k] ----------
// 128x128 tile, BK=32, 4 waves each 64x64 (4x4 of 16x16x32 MFMA).
// KHALF: for k>=256 both A and B row bases shift by 2048 rows, k -= 256 (channel-view split).
// EPI: 0 = fp16 C[m][n]; 1 = fp32 C[m][n] + residual;
//      3 = mixed conv epilogue (n0<512 -> C2[m][n]; n0>=512 -> transposed Gc[n-512][m]);
//      4 = bf16 P[m][n] = exp(acc-12) + atomic column sums L[j] += exp(acc-12)  (scores)
// SWAP: m0 from blockIdx.y, n0 from blockIdx.x (consecutive blocks share the A-tile -> L2 reuse)
// BGATHER: B-staging register path gathers the channel-view de-interleave from Y2 (mask GEMM)
// DT: 0 = fp16 MFMA, 1 = bf16 MFMA (fragment/CD layouts are dtype-independent)
template <bool KHALF, int EPI, bool SWAP, bool BGATHER, int DT>
__global__ __launch_bounds__(256) void gemm_nt(const uint16_t* __restrict__ A, const uint16_t* __restrict__ B,
                                               void* __restrict__ Cout, const float* __restrict__ resid,
                                               int lda, int ldb, int ldc, int nK,
                                               long aBatch, long bBatch, long cBatch,
                                               void* __restrict__ Cout2, int ldc2, long c2Batch,
                                               float* __restrict__ Lsum) {
    __shared__ uint16_t Al[128 * 32];
    __shared__ uint16_t Bl[128 * 32];
    const int b = blockIdx.z;
    const uint16_t* Ab = A + (long)b * aBatch;
    const uint16_t* Bb = B + (long)b * bBatch;
    const int m0 = (SWAP ? blockIdx.y : blockIdx.x) * 128;
    const int n0 = (SWAP ? blockIdx.x : blockIdx.y) * 128;
    const int tid = threadIdx.x;
    const int lane = tid & 63, wave = tid >> 6;
    const int ln = lane & 15, q = lane >> 4;
    const int wm = (wave & 1) * 64, wn = (wave >> 1) * 64;

    floatx4 acc[4][4];
#pragma unroll
    for (int i = 0; i < 4; ++i)
#pragma unroll
        for (int j = 0; j < 4; ++j) acc[i][j] = (floatx4){0.f, 0.f, 0.f, 0.f};

    for (int kt = 0; kt < nK; ++kt) {
        int k0 = kt * 32;
        int keff = k0;
        long roff = 0;
        if (KHALF && k0 >= 256) { keff = k0 - 256; roff = 2048; }
#pragma unroll
        for (int s = 0; s < 2; ++s) {
            int c = tid + s * 256;  // 512 chunks of 16B per operand
            int row = c >> 2, kq = (c & 3) * 8;
            g2lds16(Ab + ((long)(m0 + row) + roff) * lda + keff + kq, &Al[c * 8]);
            if (BGATHER) {
                int pg = n0 + row;
                int ii = pg & 2047, hh = pg >> 11;
                const uint16_t* src = Bb + (long)ii * 512 + 2 * (keff + kq);
                uint4 v0 = *(const uint4*)src;
                uint4 v1 = *(const uint4*)(src + 8);
                uint32_t* a = (uint32_t*)&v0;
                uint32_t* cc = (uint32_t*)&v1;
                uint32_t o[4];
                if (hh == 0) {
                    o[0] = (a[0] & 0xffffu) | (a[1] << 16);
                    o[1] = (a[2] & 0xffffu) | (a[3] << 16);
                    o[2] = (cc[0] & 0xffffu) | (cc[1] << 16);
                    o[3] = (cc[2] & 0xffffu) | (cc[3] << 16);
                } else {
                    o[0] = (a[0] >> 16) | (a[1] & 0xffff0000u);
                    o[1] = (a[2] >> 16) | (a[3] & 0xffff0000u);
                    o[2] = (cc[0] >> 16) | (cc[1] & 0xffff0000u);
                    o[3] = (cc[2] >> 16) | (cc[3] & 0xffff0000u);
                }
                *(uint4*)&Bl[c * 8] = *(uint4*)o;
            } else {
                g2lds16(Bb + ((long)(n0 + row) + roff) * ldb + keff + kq, &Bl[c * 8]);
            }
        }
        __syncthreads();
        short8 af[4], bfr[4];
#pragma unroll
        for (int mt = 0; mt < 4; ++mt) af[mt] = *(const short8*)&Al[(wm + mt * 16 + ln) * 32 + q * 8];
#pragma unroll
        for (int nt = 0; nt < 4; ++nt) bfr[nt] = *(const short8*)&Bl[(wn + nt * 16 + ln) * 32 + q * 8];
#pragma unroll
        for (int mt = 0; mt < 4; ++mt)
#pragma unroll
            for (int nt = 0; nt < 4; ++nt) {
                if constexpr (DT == 0) {
                    half8 ah, bh;
                    __builtin_memcpy(&ah, &af[mt], 16);
                    __builtin_memcpy(&bh, &bfr[nt], 16);
                    acc[mt][nt] = __builtin_amdgcn_mfma_f32_16x16x32_f16(ah, bh, acc[mt][nt], 0, 0, 0);
                } else {
                    acc[mt][nt] = __builtin_amdgcn_mfma_f32_16x16x32_bf16(af[mt], bfr[nt], acc[mt][nt], 0, 0, 0);
                }
            }
        __syncthreads();
    }

    // C/D layout (verified m89): col = lane&15, row = (lane>>4)*4 + reg
    if (EPI == 0 || (EPI == 3 && n0 < 512)) {
        uint16_t* C = (uint16_t*)Cout + (long)b * cBatch;
#pragma unroll
        for (int mt = 0; mt < 4; ++mt)
#pragma unroll
            for (int r = 0; r < 4; ++r) {
                int gm = m0 + wm + mt * 16 + q * 4 + r;
#pragma unroll
                for (int nt = 0; nt < 4; ++nt) {
                    int gn = n0 + wn + nt * 16 + ln;
                    C[(long)gm * ldc + gn] = f2h(acc[mt][nt][r]);
                }
            }
    } else if (EPI == 4) {
        // P = exp(S-12) stored bf16 (range-safe); L[j] accumulated from the exact fp32 exp
        uint16_t* C = (uint16_t*)Cout + (long)b * cBatch;
        float cs[4] = {0.f, 0.f, 0.f, 0.f};
#pragma unroll
        for (int mt = 0; mt < 4; ++mt)
#pragma unroll
            for (int r = 0; r < 4; ++r) {
                int gm = m0 + wm + mt * 16 + q * 4 + r;
#pragma unroll
                for (int nt = 0; nt < 4; ++nt) {
                    int gn = n0 + wn + nt * 16 + ln;
                    float e = __expf(acc[mt][nt][r] - 12.f);
                    C[(long)gm * ldc + gn] = f2bf(e);
                    cs[nt] += e;
                }
            }
#pragma unroll
        for (int nt = 0; nt < 4; ++nt) {
            float s = cs[nt];
            s += __shfl_xor(s, 16);
            s += __shfl_xor(s, 32);
            if (q == 0) atomicAdd(&Lsum[(long)b * 2048 + n0 + wn + nt * 16 + ln], s);
        }
    } else if (EPI == 1) {
        float* C = (float*)Cout + (long)b * cBatch;
        const float* X = resid + (long)b * cBatch;
#pragma unroll
        for (int mt = 0; mt < 4; ++mt)
#pragma unroll
            for (int r = 0; r < 4; ++r) {
                int gm = m0 + wm + mt * 16 + q * 4 + r;
#pragma unroll
                for (int nt = 0; nt < 4; ++nt) {
                    int gn = n0 + wn + nt * 16 + ln;
                    long idx = (long)gm * ldc + gn;
                    C[idx] = acc[mt][nt][r] + X[idx];
                }
            }
    } else {
        // transposed epilogue into Cout2: row = gn - 512, 4 contiguous m per lane -> ushort4 stores
        uint16_t* C = (uint16_t*)Cout2 + (long)b * c2Batch;
#pragma unroll
        for (int nt = 0; nt < 4; ++nt) {
            int gn2 = n0 - 512 + wn + nt * 16 + ln;
#pragma unroll
            for (int mt = 0; mt < 4; ++mt) {
                int gmB = m0 + wm + mt * 16 + q * 4;
                ushort4 u = make_ushort4(f2h(acc[mt][nt][0]), f2h(acc[mt][nt][1]), f2h(acc[mt][nt][2]),
                                         f2h(acc[mt][nt][3]));
                *(ushort4*)&C[(long)gn2 * ldc2 + gmB] = u;
            }
        }
    }
}

// ---------- launch ----------
// ws layout (total 116,843,520 B):
//   W3 @ 0 (768x512 f16: phi|theta|g) ; Wm @ 786432 (512x256 f16)
//   L  @ 1048576 (8x2048 f32)
//   A_region @ 1179648  (64 MB): Xt (32 MB) -> P (64 MB bf16)
//   B_region @ 68288512 (48 MB): C2 (32 MB) -> Y2 (16 MB) @ +0 ; Gc (16 MB) @ +32MB
// Softmax: P = bf16(exp(S-12)) written by the scores epilogue (L[j] via atomics);
// 1/L[j] folded into Gc by scale_g (fp16 -> bf16 in place); PV is a plain async bf16 GEMM.
extern "C" void kernel_launch(void* const* d_in, const int* in_sizes, int n_in, void* d_out, int out_size, void* d_ws,
                              size_t ws_size, hipStream_t stream) {
    const float* x = (const float*)d_in[0];
    const float* wphi = (const float*)d_in[1];
    const float* wtheta = (const float*)d_in[2];
    const float* wg = (const float*)d_in[3];
    const float* wmask = (const float*)d_in[4];
    float* out = (float*)d_out;
    char* ws = (char*)d_ws;

    uint16_t* W3 = (uint16_t*)(ws + 0);
    uint16_t* Wm = (uint16_t*)(ws + 786432);
    float* L = (float*)(ws + 1048576);
    char* A_region = ws + 1179648;
    char* B_region = ws + 68288512;
    uint16_t* Xt = (uint16_t*)A_region;
    uint16_t* P = (uint16_t*)A_region;
    uint16_t* C2 = (uint16_t*)B_region;
    uint16_t* Y2 = (uint16_t*)B_region;
    uint16_t* Gc = (uint16_t*)(B_region + 33554432);

    // weights -> fp16, L zeroed (one launch)
    cvt_weights<<<dim3(128, 5), 256, 0, stream>>>(wphi, wtheta, wg, wmask, W3, Wm, L);

    // x -> Xt (pixel-major fp16)
    transpose_x<<<dim3(64, 8, 8), 256, 0, stream>>>(x, Xt);

    // fused 3-conv: n=768; n0<512 -> C2[b][p][{phi|theta}], n0>=512 -> Gc[b][o][p] transposed
    gemm_nt<false, 3, false, false, 0><<<dim3(32, 6, 8), 256, 0, stream>>>(
        Xt, W3, C2, nullptr, 512, 512, 512, 16, 4096L * 512, 0, 4096L * 512, Gc, 4096, 256L * 4096, nullptr);

    // scores (k-half row shift): P[i][j] = bf16(exp(S-12)), L[j] += exp(S-12); overwrites Xt (dead)
    gemm_nt<true, 4, false, false, 0><<<dim3(16, 16, 8), 256, 0, stream>>>(
        C2 + 256, C2, P, nullptr, 512, 512, 2048, 16, 4096L * 512, 4096L * 512, 2048L * 2048, nullptr, 0, 0, L);

    // Gc[c][j] *= 1/L[j], fp16 -> bf16 in place (j = flat & 2047 under the ld-2048 view)
    scale_g<<<4096, 256, 0, stream>>>(Gc, L);

    // PV (bf16, all-async): Y2[i][c] = sum_j P[i][j] * Gc'[c][j]; SWAP grid for A-tile L2 reuse.
    // Y2 reuses C2 (dead).
    gemm_nt<false, 0, true, false, 1><<<dim3(4, 16, 8), 256, 0, stream>>>(
        P, Gc, Y2, nullptr, 2048, 2048, 512, 64, 2048L * 2048, 1048576L, 2048L * 512, nullptr, 0, 0, nullptr);

    // mask conv + residual, de-interleave folded into B-staging gather from Y2:
    // out[oc][p] = x[oc][p] + sum_ic Wm[oc][ic] * Y2[p&2047][2*ic + (p>>11)]
    gemm_nt<false, 1, false, true, 0><<<dim3(4, 32, 8), 256, 0, stream>>>(
        Wm, Y2, out, x, 256, 512, 4096, 8, 0, 1048576L, 512L * 4096, nullptr, 0, 0, nullptr);
}

// Round 6
// 295.514 us; speedup vs baseline: 1.2816x; 1.0801x over previous
//
#include <hip/hip_runtime.h>
#include <cstdint>
#include <cstddef>

// ---------- fp16/bf16 helpers ----------
typedef __attribute__((ext_vector_type(8))) _Float16 half8;
typedef __attribute__((ext_vector_type(8))) short short8;
typedef __attribute__((ext_vector_type(4))) float floatx4;

static __device__ __forceinline__ uint16_t f2h(float f) {
    _Float16 h = (_Float16)f;
    uint16_t u;
    __builtin_memcpy(&u, &h, 2);
    return u;
}
static __device__ __forceinline__ float h2f(uint16_t u) {
    _Float16 h;
    __builtin_memcpy(&h, &u, 2);
    return (float)h;
}
static __device__ __forceinline__ uint16_t f2bf(float f) {
    uint32_t u;
    __builtin_memcpy(&u, &f, 4);
    u += 0x7fffu + ((u >> 16) & 1u);  // round-to-nearest-even
    return (uint16_t)(u >> 16);
}

// async global->LDS, 16B per lane (dest = wave-uniform base + lane*16 — our chunk layout).
static __device__ __forceinline__ void g2lds16(const void* g, void* l) {
    __builtin_amdgcn_global_load_lds((__attribute__((address_space(1))) void*)g,
                                     (__attribute__((address_space(3))) void*)l, 16, 0, 0);
}

// ---------- weights fp32->fp16 (+ zero the L accumulator), one launch ----------
__global__ void cvt_weights(const float* __restrict__ wphi, const float* __restrict__ wtheta,
                            const float* __restrict__ wg, const float* __restrict__ wmask,
                            uint16_t* __restrict__ W3, uint16_t* __restrict__ Wm, float* __restrict__ L) {
    int seg = blockIdx.y;
    int i = blockIdx.x * 256 + threadIdx.x;
    if (seg == 4) {
        if (i < 16384) L[i] = 0.f;
        return;
    }
    const float* src = seg == 0 ? wphi : seg == 1 ? wtheta : seg == 2 ? wg : wmask;
    uint16_t* dst = seg < 3 ? W3 + seg * 131072 : Wm;
    int base = i * 4;  // grid.x=128 -> base < 131072 exactly
    float4 v = *(const float4*)(src + base);
    *(ushort4*)(dst + base) = make_ushort4(f2h(v.x), f2h(v.y), f2h(v.z), f2h(v.w));
}

// ---------- transpose x: (b,512,4096) f32 -> Xt (b,4096,512) f16 ----------
__global__ __launch_bounds__(256) void transpose_x(const float* __restrict__ x, uint16_t* __restrict__ xt) {
    __shared__ uint16_t tile[64][66];
    int b = blockIdx.z, p0 = blockIdx.x * 64, c0 = blockIdx.y * 64;
    int t0 = threadIdx.x & 63, t1 = threadIdx.x >> 6;
    const float* xb = x + ((long)b * 512 + c0) * 4096 + p0;
#pragma unroll
    for (int r = 0; r < 16; ++r) {
        int cc = t1 * 16 + r;
        tile[cc][t0] = f2h(xb[(long)cc * 4096 + t0]);
    }
    __syncthreads();
    uint16_t* xtb = xt + ((long)b * 4096 + p0) * 512 + c0;
#pragma unroll
    for (int r = 0; r < 16; ++r) {
        int pp = t1 * 16 + r;
        xtb[(long)pp * 512 + t0] = tile[t0][pp];
    }
}

// ---------- scale+normalize g: Gc (fp16) -> Gc (bf16), element f *= 1/L[f & 2047] ----------
// Gc viewed flat per batch: [512 rows][2048 j]; the PV k-index j = flat & 2047.
__global__ void scale_g(uint16_t* __restrict__ gc, const float* __restrict__ L) {
    long t = (long)blockIdx.x * 256 + threadIdx.x;  // 1,048,576 threads, 8 elems each
    long base = t * 8;
    int j0 = (int)(base & 2047);
    int b = (int)(base >> 20);  // 256*4096 elems per batch
    const float* Lp = L + (long)b * 2048 + j0;
    float4 l0 = *(const float4*)Lp;
    float4 l1 = *(const float4*)(Lp + 4);
    float rr[8] = {1.f / l0.x, 1.f / l0.y, 1.f / l0.z, 1.f / l0.w, 1.f / l1.x, 1.f / l1.y, 1.f / l1.z, 1.f / l1.w};
    uint4 v = *(uint4*)(gc + base);
    uint32_t* pv = (uint32_t*)&v;
    uint32_t o[4];
#pragma unroll
    for (int e = 0; e < 4; ++e) {
        float a = h2f((uint16_t)(pv[e] & 0xffffu)) * rr[2 * e];
        float c = h2f((uint16_t)(pv[e] >> 16)) * rr[2 * e + 1];
        o[e] = (uint32_t)f2bf(a) | ((uint32_t)f2bf(c) << 16);
    }
    *(uint4*)(gc + base) = *(uint4*)o;
}

// ---------- NT GEMM: C[m][n] = sum_k A[m][k]*B[n][k] ----------
// 128x128 tile, BK=64 staged as TWO stacked [128][32] LDS panels (keeps the conflict-free
// ds_read_b128 bank pattern; a fused [128][64] row stride would be 16-way conflicted and
// global_load_lds forbids padding). Halves the barrier count vs BK=32.
// nK = K/64. 4 waves each 64x64 (4x4 of 16x16x32 MFMA, 2 k-steps per iter).
// KHALF: for k>=256 both A and B row bases shift by 2048 rows, k -= 256 (channel-view split).
// EPI: 0 = fp16 C[m][n]; 1 = fp32 C[m][n] + residual;
//      3 = mixed conv epilogue (n0<512 -> C2[m][n]; n0>=512 -> transposed Gc[n-512][m]);
//      4 = bf16 P[m][n] = exp(acc-12) + atomic column sums L[j] += exp(acc-12)  (scores)
// SWAP: m0 from blockIdx.y, n0 from blockIdx.x (consecutive blocks share the A-tile -> L2 reuse)
// BGATHER: B-staging register path gathers the channel-view de-interleave from Y2 (mask GEMM)
// DT: 0 = fp16 MFMA, 1 = bf16 MFMA (fragment/CD layouts are dtype-independent)
template <bool KHALF, int EPI, bool SWAP, bool BGATHER, int DT>
__global__ __launch_bounds__(256) void gemm_nt(const uint16_t* __restrict__ A, const uint16_t* __restrict__ B,
                                               void* __restrict__ Cout, const float* __restrict__ resid,
                                               int lda, int ldb, int ldc, int nK,
                                               long aBatch, long bBatch, long cBatch,
                                               void* __restrict__ Cout2, int ldc2, long c2Batch,
                                               float* __restrict__ Lsum) {
    __shared__ uint16_t Al[2 * 128 * 32];
    __shared__ uint16_t Bl[2 * 128 * 32];
    const int b = blockIdx.z;
    const uint16_t* Ab = A + (long)b * aBatch;
    const uint16_t* Bb = B + (long)b * bBatch;
    const int m0 = (SWAP ? blockIdx.y : blockIdx.x) * 128;
    const int n0 = (SWAP ? blockIdx.x : blockIdx.y) * 128;
    const int tid = threadIdx.x;
    const int lane = tid & 63, wave = tid >> 6;
    const int ln = lane & 15, q = lane >> 4;
    const int wm = (wave & 1) * 64, wn = (wave >> 1) * 64;

    floatx4 acc[4][4];
#pragma unroll
    for (int i = 0; i < 4; ++i)
#pragma unroll
        for (int j = 0; j < 4; ++j) acc[i][j] = (floatx4){0.f, 0.f, 0.f, 0.f};

    for (int kt = 0; kt < nK; ++kt) {
        int k0 = kt * 64;
#pragma unroll
        for (int half = 0; half < 2; ++half) {
            int kh = k0 + half * 32;
            int keff = kh;
            long roff = 0;
            if (KHALF && kh >= 256) { keff = kh - 256; roff = 2048; }
            uint16_t* AlH = &Al[half * 4096];
            uint16_t* BlH = &Bl[half * 4096];
#pragma unroll
            for (int s = 0; s < 2; ++s) {
                int c = tid + s * 256;  // 512 chunks of 16B per operand-panel
                int row = c >> 2, kq = (c & 3) * 8;
                g2lds16(Ab + ((long)(m0 + row) + roff) * lda + keff + kq, &AlH[c * 8]);
                if (BGATHER) {
                    int pg = n0 + row;
                    int ii = pg & 2047, hh = pg >> 11;
                    const uint16_t* src = Bb + (long)ii * 512 + 2 * (keff + kq);
                    uint4 v0 = *(const uint4*)src;
                    uint4 v1 = *(const uint4*)(src + 8);
                    uint32_t* a = (uint32_t*)&v0;
                    uint32_t* cc = (uint32_t*)&v1;
                    uint32_t o[4];
                    if (hh == 0) {
                        o[0] = (a[0] & 0xffffu) | (a[1] << 16);
                        o[1] = (a[2] & 0xffffu) | (a[3] << 16);
                        o[2] = (cc[0] & 0xffffu) | (cc[1] << 16);
                        o[3] = (cc[2] & 0xffffu) | (cc[3] << 16);
                    } else {
                        o[0] = (a[0] >> 16) | (a[1] & 0xffff0000u);
                        o[1] = (a[2] >> 16) | (a[3] & 0xffff0000u);
                        o[2] = (cc[0] >> 16) | (cc[1] & 0xffff0000u);
                        o[3] = (cc[2] >> 16) | (cc[3] & 0xffff0000u);
                    }
                    *(uint4*)&BlH[c * 8] = *(uint4*)o;
                } else {
                    g2lds16(Bb + ((long)(n0 + row) + roff) * ldb + keff + kq, &BlH[c * 8]);
                }
            }
        }
        __syncthreads();
#pragma unroll
        for (int half = 0; half < 2; ++half) {
            const uint16_t* AlH = &Al[half * 4096];
            const uint16_t* BlH = &Bl[half * 4096];
            short8 af[4], bfr[4];
#pragma unroll
            for (int mt = 0; mt < 4; ++mt) af[mt] = *(const short8*)&AlH[(wm + mt * 16 + ln) * 32 + q * 8];
#pragma unroll
            for (int nt = 0; nt < 4; ++nt) bfr[nt] = *(const short8*)&BlH[(wn + nt * 16 + ln) * 32 + q * 8];
#pragma unroll
            for (int mt = 0; mt < 4; ++mt)
#pragma unroll
                for (int nt = 0; nt < 4; ++nt) {
                    if constexpr (DT == 0) {
                        half8 ah, bh;
                        __builtin_memcpy(&ah, &af[mt], 16);
                        __builtin_memcpy(&bh, &bfr[nt], 16);
                        acc[mt][nt] = __builtin_amdgcn_mfma_f32_16x16x32_f16(ah, bh, acc[mt][nt], 0, 0, 0);
                    } else {
                        acc[mt][nt] = __builtin_amdgcn_mfma_f32_16x16x32_bf16(af[mt], bfr[nt], acc[mt][nt], 0, 0, 0);
                    }
                }
        }
        __syncthreads();
    }

    // C/D layout (verified m89): col = lane&15, row = (lane>>4)*4 + reg
    if (EPI == 0 || (EPI == 3 && n0 < 512)) {
        uint16_t* C = (uint16_t*)Cout + (long)b * cBatch;
#pragma unroll
        for (int mt = 0; mt < 4; ++mt)
#pragma unroll
            for (int r = 0; r < 4; ++r) {
                int gm = m0 + wm + mt * 16 + q * 4 + r;
#pragma unroll
                for (int nt = 0; nt < 4; ++nt) {
                    int gn = n0 + wn + nt * 16 + ln;
                    C[(long)gm * ldc + gn] = f2h(acc[mt][nt][r]);
                }
            }
    } else if (EPI == 4) {
        // P = exp(S-12) stored bf16 (range-safe); L[j] accumulated from the exact fp32 exp
        uint16_t* C = (uint16_t*)Cout + (long)b * cBatch;
        float cs[4] = {0.f, 0.f, 0.f, 0.f};
#pragma unroll
        for (int mt = 0; mt < 4; ++mt)
#pragma unroll
            for (int r = 0; r < 4; ++r) {
                int gm = m0 + wm + mt * 16 + q * 4 + r;
#pragma unroll
                for (int nt = 0; nt < 4; ++nt) {
                    int gn = n0 + wn + nt * 16 + ln;
                    float e = __expf(acc[mt][nt][r] - 12.f);
                    C[(long)gm * ldc + gn] = f2bf(e);
                    cs[nt] += e;
                }
            }
#pragma unroll
        for (int nt = 0; nt < 4; ++nt) {
            float s = cs[nt];
            s += __shfl_xor(s, 16);
            s += __shfl_xor(s, 32);
            if (q == 0) atomicAdd(&Lsum[(long)b * 2048 + n0 + wn + nt * 16 + ln], s);
        }
    } else if (EPI == 1) {
        float* C = (float*)Cout + (long)b * cBatch;
        const float* X = resid + (long)b * cBatch;
#pragma unroll
        for (int mt = 0; mt < 4; ++mt)
#pragma unroll
            for (int r = 0; r < 4; ++r) {
                int gm = m0 + wm + mt * 16 + q * 4 + r;
#pragma unroll
                for (int nt = 0; nt < 4; ++nt) {
                    int gn = n0 + wn + nt * 16 + ln;
                    long idx = (long)gm * ldc + gn;
                    C[idx] = acc[mt][nt][r] + X[idx];
                }
            }
    } else {
        // transposed epilogue into Cout2: row = gn - 512, 4 contiguous m per lane -> ushort4 stores
        uint16_t* C = (uint16_t*)Cout2 + (long)b * c2Batch;
#pragma unroll
        for (int nt = 0; nt < 4; ++nt) {
            int gn2 = n0 - 512 + wn + nt * 16 + ln;
#pragma unroll
            for (int mt = 0; mt < 4; ++mt) {
                int gmB = m0 + wm + mt * 16 + q * 4;
                ushort4 u = make_ushort4(f2h(acc[mt][nt][0]), f2h(acc[mt][nt][1]), f2h(acc[mt][nt][2]),
                                         f2h(acc[mt][nt][3]));
                *(ushort4*)&C[(long)gn2 * ldc2 + gmB] = u;
            }
        }
    }
}

// ---------- launch ----------
// ws layout (total 116,843,520 B):
//   W3 @ 0 (768x512 f16: phi|theta|g) ; Wm @ 786432 (512x256 f16)
//   L  @ 1048576 (8x2048 f32)
//   A_region @ 1179648  (64 MB): Xt (32 MB) -> P (64 MB bf16)
//   B_region @ 68288512 (48 MB): C2 (32 MB) -> Y2 (16 MB) @ +0 ; Gc (16 MB) @ +32MB
// Softmax: P = bf16(exp(S-12)) written by the scores epilogue (L[j] via atomics);
// 1/L[j] folded into Gc by scale_g (fp16 -> bf16 in place); PV is a plain async bf16 GEMM.
extern "C" void kernel_launch(void* const* d_in, const int* in_sizes, int n_in, void* d_out, int out_size, void* d_ws,
                              size_t ws_size, hipStream_t stream) {
    const float* x = (const float*)d_in[0];
    const float* wphi = (const float*)d_in[1];
    const float* wtheta = (const float*)d_in[2];
    const float* wg = (const float*)d_in[3];
    const float* wmask = (const float*)d_in[4];
    float* out = (float*)d_out;
    char* ws = (char*)d_ws;

    uint16_t* W3 = (uint16_t*)(ws + 0);
    uint16_t* Wm = (uint16_t*)(ws + 786432);
    float* L = (float*)(ws + 1048576);
    char* A_region = ws + 1179648;
    char* B_region = ws + 68288512;
    uint16_t* Xt = (uint16_t*)A_region;
    uint16_t* P = (uint16_t*)A_region;
    uint16_t* C2 = (uint16_t*)B_region;
    uint16_t* Y2 = (uint16_t*)B_region;
    uint16_t* Gc = (uint16_t*)(B_region + 33554432);

    // weights -> fp16, L zeroed (one launch)
    cvt_weights<<<dim3(128, 5), 256, 0, stream>>>(wphi, wtheta, wg, wmask, W3, Wm, L);

    // x -> Xt (pixel-major fp16)
    transpose_x<<<dim3(64, 8, 8), 256, 0, stream>>>(x, Xt);

    // fused 3-conv: n=768; n0<512 -> C2[b][p][{phi|theta}], n0>=512 -> Gc[b][o][p] transposed
    gemm_nt<false, 3, false, false, 0><<<dim3(32, 6, 8), 256, 0, stream>>>(
        Xt, W3, C2, nullptr, 512, 512, 512, 8, 4096L * 512, 0, 4096L * 512, Gc, 4096, 256L * 4096, nullptr);

    // scores (k-half row shift): P[i][j] = bf16(exp(S-12)), L[j] += exp(S-12); overwrites Xt (dead)
    gemm_nt<true, 4, false, false, 0><<<dim3(16, 16, 8), 256, 0, stream>>>(
        C2 + 256, C2, P, nullptr, 512, 512, 2048, 8, 4096L * 512, 4096L * 512, 2048L * 2048, nullptr, 0, 0, L);

    // Gc[c][j] *= 1/L[j], fp16 -> bf16 in place (j = flat & 2047 under the ld-2048 view)
    scale_g<<<4096, 256, 0, stream>>>(Gc, L);

    // PV (bf16, all-async): Y2[i][c] = sum_j P[i][j] * Gc'[c][j]; SWAP grid for A-tile L2 reuse.
    // Y2 reuses C2 (dead).
    gemm_nt<false, 0, true, false, 1><<<dim3(4, 16, 8), 256, 0, stream>>>(
        P, Gc, Y2, nullptr, 2048, 2048, 512, 32, 2048L * 2048, 1048576L, 2048L * 512, nullptr, 0, 0, nullptr);

    // mask conv + residual, de-interleave folded into B-staging gather from Y2:
    // out[oc][p] = x[oc][p] + sum_ic Wm[oc][ic] * Y2[p&2047][2*ic + (p>>11)]
    gemm_nt<false, 1, false, true, 0><<<dim3(4, 32, 8), 256, 0, stream>>>(
        Wm, Y2, out, x, 256, 512, 4096, 4, 0, 1048576L, 512L * 4096, nullptr, 0, 0, nullptr);
}